// Round 20
// baseline (120.286 us; speedup 1.0000x reference)
//
#include <hip/hip_runtime.h>

#define N_PTS  20000
#define NG     128                  // grid NG x NG over [-6,6]^2
#define NC     (NG * NG)            // 16384 cells per cloud
#define GMIN   (-6.0f)
#define GINV   (NG / 12.0f)
#define MARGIN 5e-4f                // >> 2e-5 worst-case |P_np - d_true^2|
#define SSTRIDE (N_PTS / 64)        // 312; 63*312 = 19656 < 20000
#define QB79   79                   // fallback

// ---- numpy-exact helpers (proven rounds 2/5/9/10/11/14) ----
__device__ __forceinline__ float np_self_dot(float x, float y, float z) {
    return __fadd_rn(__fadd_rn(__fmul_rn(x, x), __fmul_rn(y, y)),
                     __fmul_rn(z, z));
}
__device__ __forceinline__ unsigned ordmap(float f) {
    unsigned b = __float_as_uint(f);
    return (b & 0x80000000u) ? ~b : (b | 0x80000000u);
}
__device__ __forceinline__ float invord(unsigned h) {
    return __uint_as_float((h & 0x80000000u) ? (h ^ 0x80000000u) : ~h);
}
__device__ __forceinline__ int cellC(float v) {
    int c = (int)((v - GMIN) * GINV);
    return c < 0 ? 0 : (c > NG - 1 ? NG - 1 : c);
}
__device__ __forceinline__ unsigned long long wave_min_u64(unsigned long long k) {
    #pragma unroll
    for (int m = 1; m < 64; m <<= 1) {
        unsigned long long o = __shfl_xor(k, m, 64);
        k = (o < k) ? o : k;
    }
    return k;
}

// Single-query evaluation, parameterized by query regs + key (bit-identical
// numerics to r9-r33: numpy-exact P; key=(ordmap(P)<<32|idx)).
#define EVALQ(r, QX, QY, QZ, SQ, KEY)                                      \
    {   float sr = np_self_dot((r).x, (r).y, (r).z);                       \
        float zz = __fadd_rn(__fadd_rn(__fmul_rn(QX, (r).x),               \
                                       __fmul_rn(QY, (r).y)),              \
                             __fmul_rn(QZ, (r).z));                        \
        float P  = __fsub_rn(__fadd_rn(SQ, sr), __fadd_rn(zz, zz));        \
        unsigned long long kk =                                            \
            ((unsigned long long)ordmap(P) << 32) | __float_as_uint((r).w);\
        KEY = (kk < KEY) ? kk : KEY; }

// Process <=32 rows whose bounds sit in register BND (lanes 0..31 = row
// starts, lanes 32..63 = row ends): triples via shfl, flat 3-interval
// stream, 2-deep pipelined. (r23/r28/r29 PROVEN machinery — seed path.)
#define SCAN_ROWS32(BND, ROWS, QX, QY, QZ, SQ, KEY)                        \
    for (int r0 = 0; r0 < (ROWS); r0 += 3) {                               \
        int i1 = r0 + 1 < (ROWS) ? r0 + 1 : (ROWS) - 1;                    \
        int i2 = r0 + 2 < (ROWS) ? r0 + 2 : (ROWS) - 1;                    \
        int L0 = __shfl(BND, r0, 64), H0 = __shfl(BND, 32 + r0, 64);       \
        int L1 = __shfl(BND, i1, 64), H1 = __shfl(BND, 32 + i1, 64);       \
        int L2 = __shfl(BND, i2, 64), H2 = __shfl(BND, 32 + i2, 64);       \
        int d0 = H0 - L0;                                                  \
        int d1 = (r0 + 1 < (ROWS)) ? H1 - L1 : 0;                          \
        int d2 = (r0 + 2 < (ROWS)) ? H2 - L2 : 0;                          \
        int s01 = d0 + d1, tot = s01 + d2;                                 \
        int t = lane;                                                      \
        if (t < tot) {                                                     \
            int p = t < d0 ? L0 + t : t < s01 ? L1 + (t - d0)              \
                                              : L2 + (t - s01);            \
            float4 rc = rs[p];                                             \
            for (t += 64; t < tot; t += 64) {                              \
                int pn = t < d0 ? L0 + t : t < s01 ? L1 + (t - d0)         \
                                                   : L2 + (t - s01);       \
                float4 rn = rs[pn];                                        \
                EVALQ(rc, QX, QY, QZ, SQ, KEY)                             \
                rc = rn;                                                   \
            }                                                              \
            EVALQ(rc, QX, QY, QZ, SQ, KEY)                                 \
        }                                                                  \
    }

// Phase-2 SPAN stream (r34): scan the contiguous interval [LO,HI) that
// contains the W-box (row-major cell-sorted => box is inside ONE span —
// r22-proven superset; every extra point is a genuine candidate; min/
// argmin exact). Replaces ~10 SERIAL triple-segments for tail boxes with
// one 4-deep-pipelined stream. Sparse fringe rows => span ~= clipped box.
#define SPAN_STREAM(LO, HI, QX, QY, QZ, SQ, KEY)                           \
    {   int p = (LO) + lane;                                               \
        for (; p + 192 < (HI); p += 256) {                                 \
            float4 r0 = rs[p],       r1 = rs[p + 64];                      \
            float4 r2 = rs[p + 128], r3 = rs[p + 192];                     \
            EVALQ(r0, QX, QY, QZ, SQ, KEY)                                 \
            EVALQ(r1, QX, QY, QZ, SQ, KEY)                                 \
            EVALQ(r2, QX, QY, QZ, SQ, KEY)                                 \
            EVALQ(r3, QX, QY, QZ, SQ, KEY)                                 \
        }                                                                  \
        for (; p + 64 < (HI); p += 128) {                                  \
            float4 r0 = rs[p], r1 = rs[p + 64];                            \
            EVALQ(r0, QX, QY, QZ, SQ, KEY)                                 \
            EVALQ(r1, QX, QY, QZ, SQ, KEY)                                 \
        }                                                                  \
        if (p < (HI)) { float4 r0 = rs[p]; EVALQ(r0, QX, QY, QZ, SQ, KEY) }\
    }

// ---- build A1 (r16/r18, PROVEN): wide parallel histogram, global atomics ----
__global__ __launch_bounds__(256) void k_hist(
    const float* __restrict__ preds, const float* __restrict__ gts,
    int* __restrict__ cursor)
{
    int t = blockIdx.x * 256 + threadIdx.x;
    if (t >= 2 * N_PTS) return;
    int cl = t / N_PTS, i = t - cl * N_PTS;
    const float* src = cl ? gts : preds;
    int cell = cellC(src[i*3+0]) * NG + cellC(src[i*3+1]);
    atomicAdd(&cursor[cl * NC + cell], 1);
}

// ---- build A2 (r22, PROVEN): scan via shfl wave-scans, 2 barriers ----
__global__ __launch_bounds__(1024) void k_scan(
    int* __restrict__ cursor, int* __restrict__ bstart)
{
    __shared__ int wsum[16];
    __shared__ int wpre[16];
    int cl = blockIdx.x, t = threadIdx.x;
    int wave = t >> 6, lane = t & 63;

    int base = cl * NC + t * 16;                    // 64B-aligned (ws layout)
    const int4* c4 = (const int4*)(cursor + base);
    int4 a = c4[0], b = c4[1], c = c4[2], d = c4[3];
    int v[16] = { a.x, a.y, a.z, a.w, b.x, b.y, b.z, b.w,
                  c.x, c.y, c.z, c.w, d.x, d.y, d.z, d.w };
    int s = 0;
    #pragma unroll
    for (int i = 0; i < 16; ++i) s += v[i];

    int ps = s;                                     // inclusive 64-lane scan
    #pragma unroll
    for (int m = 1; m < 64; m <<= 1) {
        int o = __shfl_up(ps, m, 64);
        if (lane >= m) ps += o;
    }
    if (lane == 63) wsum[wave] = ps;
    __syncthreads();
    if (t < 16) {
        int x = wsum[t];
        int px = x;                                 // inclusive 16-scan
        #pragma unroll
        for (int m = 1; m < 16; m <<= 1) {
            int o = __shfl_up(px, m, 16);
            if ((t & 15) >= m) px += o;
        }
        wpre[t] = px - x;                           // exclusive wave prefix
    }
    __syncthreads();

    int run = wpre[wave] + (ps - s);                // exclusive thread prefix
    #pragma unroll
    for (int i = 0; i < 16; ++i) {
        bstart[cl * (NC + 1) + t * 16 + i] = run;
        cursor[base + i] = run;
        run += v[i];
    }
    if (t == 1023) bstart[cl * (NC + 1) + NC] = run;   // == N_PTS
}

// ---- build B (r15/r18, PROVEN): wide scatter into cell-sorted order ----
__global__ __launch_bounds__(256) void k_scatter(
    const float* __restrict__ preds, const float* __restrict__ gts,
    int* __restrict__ cursor, float4* __restrict__ sorted)
{
    int t = blockIdx.x * 256 + threadIdx.x;
    if (t >= 2 * N_PTS) return;
    int cl = t / N_PTS, i = t - cl * N_PTS;
    const float* src = cl ? gts : preds;
    float x = src[i*3+0], y = src[i*3+1], z = src[i*3+2];
    int cell = cellC(x) * NG + cellC(y);
    int pos = atomicAdd(&cursor[cl * NC + cell], 1);
    sorted[(size_t)cl * N_PTS + pos] = make_float4(x, y, z, __int_as_float(i));
}

// ---- main (r34): r29 EXACT (best verified, 118.7us) with ONE change:
// phase 2 uses the SPAN stream instead of SCAN_RECT row-triples.
// Rationale: the tail governs duration (r31 proved bidirectionally);
// tail cost = fringe W-boxes of 20-40 rows scanned as ~10 SERIAL
// triple-segments. The span [cs[txL*NG+tyL], cs[txR*NG+tyR+1]) contains
// the box (r22-proven superset, min/argmin exact) and streams as ONE
// contiguous 4-deep-pipelined loop; fringe rows are sparse so span ~=
// clipped box there. Center over-scan is cheap streamed throughput
// (r22) and phase-2 is rare at the center (5x5 seed, W~1.3 cells).
// Numerics bit-identical: numpy-exact P; key=(ordmap(P)<<32|idx);
// wave-min == numpy first-occurrence argmin; samp EVALQ valid bound;
// W-certificate W^2 = d_seed + MARGIN; superset/rescan idempotent.
__global__ __launch_bounds__(64) void k_main(
    const float4* __restrict__ sorted, const int* __restrict__ bstart,
    float* __restrict__ out)
{
    int wid  = blockIdx.x;                                 // 0..19999 (pair)
    int lane = threadIdx.x;                                // 0..63
    int q0   = wid * 2;                                    // N_PTS even =>
    int dir  = q0 / N_PTS;                                 // pair same dir
    int qp0  = q0 - dir * N_PTS;
    int rcl  = 1 - dir;

    const float4* rs = sorted + (size_t)rcl * N_PTS;
    const int*    cs = bstart + rcl * (NC + 1);

    float4 samp = rs[lane * SSTRIDE];                  // independent, early
    float4 qva  = sorted[(size_t)dir * N_PTS + qp0];   // wave-broadcast
    float4 qvb  = sorted[(size_t)dir * N_PTS + qp0 + 1];
    int oa = __float_as_int(qva.w), ob = __float_as_int(qvb.w);
    float qax = qva.x, qay = qva.y, qaz = qva.z;
    float qbx = qvb.x, qby = qvb.y, qbz = qvb.z;
    float sqa = np_self_dot(qax, qay, qaz);
    float sqb = np_self_dot(qbx, qby, qbz);

    unsigned long long ka = ~0ULL, kb = ~0ULL;
    int l31 = lane & 31;

    // both 5x5 seed boxes; BOTH bounds loads issued before either stream
    int cxa = cellC(qax), cya = cellC(qay);
    int cxb = cellC(qbx), cyb = cellC(qby);
    int sxLa = cxa > 1 ? cxa - 2 : 0, sxRa = cxa < NG-2 ? cxa + 2 : NG-1;
    int syLa = cya > 1 ? cya - 2 : 0, syRa = cya < NG-2 ? cya + 2 : NG-1;
    int sxLb = cxb > 1 ? cxb - 2 : 0, sxRb = cxb < NG-2 ? cxb + 2 : NG-1;
    int syLb = cyb > 1 ? cyb - 2 : 0, syRb = cyb < NG-2 ? cyb + 2 : NG-1;
    int nrsA = sxRa - sxLa + 1, nrsB = sxRb - sxLb + 1;    // 3..5
    int xrA  = sxLa + (l31 < nrsA ? l31 : nrsA - 1);
    int xrB  = sxLb + (l31 < nrsB ? l31 : nrsB - 1);
    int colA = (lane < 32) ? syLa : (syRa + 1);
    int colB = (lane < 32) ? syLb : (syRb + 1);
    int bndA = cs[xrA * NG + colA];                        // 2 loads
    int bndB = cs[xrB * NG + colB];                        //  in flight

    SCAN_ROWS32(bndA, nrsA, qax, qay, qaz, sqa, ka)        // seed A
    SCAN_ROWS32(bndB, nrsB, qbx, qby, qbz, sqb, kb)        // seed B
    EVALQ(samp, qax, qay, qaz, sqa, ka)     // valid upper bound for A
    EVALQ(samp, qbx, qby, qbz, sqb, kb)     // valid upper bound for B

    ka = wave_min_u64(ka);
    kb = wave_min_u64(kb);

    // phase 2 per query — SPAN stream over the containing interval
    float Wa = sqrtf(invord((unsigned)(ka >> 32)) + MARGIN);
    float Wb = sqrtf(invord((unsigned)(kb >> 32)) + MARGIN);
    int txLa = cellC(qax - Wa), txRa = cellC(qax + Wa);
    int tyLa = cellC(qay - Wa), tyRa = cellC(qay + Wa);
    int txLb = cellC(qbx - Wb), txRb = cellC(qbx + Wb);
    int tyLb = cellC(qby - Wb), tyRb = cellC(qby + Wb);
    bool p2a = !(txLa >= sxLa && txRa <= sxRa && tyLa >= syLa && tyRa <= syRa);
    bool p2b = !(txLb >= sxLb && txRb <= sxRb && tyLb >= syLb && tyRb <= syRb);
    if (p2a | p2b) {                        // issue both bound pairs first
        int loA = 0, hiA = 0, loB = 0, hiB = 0;
        if (p2a) { loA = cs[txLa * NG + tyLa];
                   hiA = cs[txRa * NG + tyRa + 1]; }
        if (p2b) { loB = cs[txLb * NG + tyLb];
                   hiB = cs[txRb * NG + tyRb + 1]; }
        if (p2a) {
            SPAN_STREAM(loA, hiA, qax, qay, qaz, sqa, ka)
            ka = wave_min_u64(ka);
        }
        if (p2b) {
            SPAN_STREAM(loB, hiB, qbx, qby, qbz, sqb, kb)
            kb = wave_min_u64(kb);
        }
    }

    if (lane == 0) {
        out[dir * N_PTS + oa]       = invord((unsigned)(ka >> 32));
        out[(2 + dir) * N_PTS + oa] = (float)(unsigned)(ka & 0xFFFFFFFFu);
        out[dir * N_PTS + ob]       = invord((unsigned)(kb >> 32));
        out[(2 + dir) * N_PTS + ob] = (float)(unsigned)(kb & 0xFFFFFFFFu);
    }
}

// ---- fallback (tiny workspace): brute-force direct kernel (proven r2) ----
__device__ __forceinline__ float np_pair(float sq, float sr,
                                         float qx, float qy, float qz,
                                         float rx, float ry, float rz) {
    float zz = __fadd_rn(__fadd_rn(__fmul_rn(qx, rx), __fmul_rn(qy, ry)),
                         __fmul_rn(qz, rz));
    return __fsub_rn(__fadd_rn(sq, sr), __fadd_rn(zz, zz));
}

__global__ __launch_bounds__(256) void chamfer_direct_kernel(
    const float* __restrict__ preds, const float* __restrict__ gts,
    float* __restrict__ out)
{
    __shared__ float4 spts[256];
    int bid = blockIdx.x;
    int dir = bid / QB79;
    int qb  = bid - dir * QB79;
    int q   = qb * 256 + threadIdx.x;

    const float* qpts = (dir == 0) ? preds : gts;
    const float* rpts = (dir == 0) ? gts   : preds;

    int qc = (q < N_PTS) ? q : (N_PTS - 1);
    float qx = qpts[qc*3+0], qy = qpts[qc*3+1], qz = qpts[qc*3+2];
    float sq = np_self_dot(qx, qy, qz);
    float best = 3.4e38f;
    int   bidx = 0;

    for (int t = 0; t < N_PTS; t += 256) {
        int cnt = min(256, N_PTS - t);
        __syncthreads();
        if ((int)threadIdx.x < cnt) {
            int j = t + threadIdx.x;
            float rx = rpts[j*3+0], ry = rpts[j*3+1], rz = rpts[j*3+2];
            spts[threadIdx.x] = make_float4(rx, ry, rz, np_self_dot(rx, ry, rz));
        }
        __syncthreads();
        for (int k = 0; k < cnt; ++k) {
            float4 r = spts[k];
            float d = np_pair(sq, r.w, qx, qy, qz, r.x, r.y, r.z);
            if (d < best) { best = d; bidx = t + k; }
        }
    }
    if (q < N_PTS) {
        out[dir * N_PTS + q]       = best;
        out[(2 + dir) * N_PTS + q] = (float)bidx;
    }
}

extern "C" void kernel_launch(void* const* d_in, const int* in_sizes, int n_in,
                              void* d_out, int out_size, void* d_ws, size_t ws_size,
                              hipStream_t stream) {
    const float* preds = (const float*)d_in[0];  // [20000, 3]
    const float* gts   = (const float*)d_in[1];  // [1, 20000, 3]
    float* out = (float*)d_out;

    char* w = (char*)d_ws;
    size_t sorted_b = (size_t)2 * N_PTS * sizeof(float4);   // 640000
    size_t bstart_b = (size_t)2 * (NC + 1) * sizeof(int);   // 131080
    size_t cursor_b = (size_t)2 * NC * sizeof(int);         // 131072
    size_t need = sorted_b + bstart_b + cursor_b;

    if (ws_size >= need) {
        float4* sorted = (float4*)w;
        int* bstart = (int*)(w + sorted_b);
        int* cursor = (int*)(w + sorted_b + bstart_b);

        hipMemsetAsync(cursor, 0, cursor_b, stream);
        k_hist<<<(2 * N_PTS + 255) / 256, 256, 0, stream>>>(preds, gts, cursor);
        k_scan<<<2, 1024, 0, stream>>>(cursor, bstart);
        k_scatter<<<(2 * N_PTS + 255) / 256, 256, 0, stream>>>(
            preds, gts, cursor, sorted);
        k_main<<<N_PTS, 64, 0, stream>>>(sorted, bstart, out);
    } else {
        chamfer_direct_kernel<<<2 * QB79, 256, 0, stream>>>(preds, gts, out);
    }
}

// Round 21
// 117.870 us; speedup vs baseline: 1.0205x; 1.0205x over previous
//
#include <hip/hip_runtime.h>

#define N_PTS  20000
#define NG     128                  // grid NG x NG over [-6,6]^2
#define NC     (NG * NG)            // 16384 cells per cloud
#define GMIN   (-6.0f)
#define GINV   (NG / 12.0f)
#define MARGIN 5e-4f                // >> 2e-5 worst-case |P_np - d_true^2|
#define SSTRIDE (N_PTS / 64)        // 312; 63*312 = 19656 < 20000
#define QB79   79                   // fallback

// ---- numpy-exact helpers (proven rounds 2/5/9/10/11/14) ----
__device__ __forceinline__ float np_self_dot(float x, float y, float z) {
    return __fadd_rn(__fadd_rn(__fmul_rn(x, x), __fmul_rn(y, y)),
                     __fmul_rn(z, z));
}
__device__ __forceinline__ unsigned ordmap(float f) {
    unsigned b = __float_as_uint(f);
    return (b & 0x80000000u) ? ~b : (b | 0x80000000u);
}
__device__ __forceinline__ float invord(unsigned h) {
    return __uint_as_float((h & 0x80000000u) ? (h ^ 0x80000000u) : ~h);
}
__device__ __forceinline__ int cellC(float v) {
    int c = (int)((v - GMIN) * GINV);
    return c < 0 ? 0 : (c > NG - 1 ? NG - 1 : c);
}
__device__ __forceinline__ unsigned long long wave_min_u64(unsigned long long k) {
    #pragma unroll
    for (int m = 1; m < 64; m <<= 1) {
        unsigned long long o = __shfl_xor(k, m, 64);
        k = (o < k) ? o : k;
    }
    return k;
}

// Single-query evaluation, parameterized by query regs + key (bit-identical
// numerics to r9-r34: numpy-exact P; key=(ordmap(P)<<32|idx)).
#define EVALQ(r, QX, QY, QZ, SQ, KEY)                                      \
    {   float sr = np_self_dot((r).x, (r).y, (r).z);                       \
        float zz = __fadd_rn(__fadd_rn(__fmul_rn(QX, (r).x),               \
                                       __fmul_rn(QY, (r).y)),              \
                             __fmul_rn(QZ, (r).z));                        \
        float P  = __fsub_rn(__fadd_rn(SQ, sr), __fadd_rn(zz, zz));        \
        unsigned long long kk =                                            \
            ((unsigned long long)ordmap(P) << 32) | __float_as_uint((r).w);\
        KEY = (kk < KEY) ? kk : KEY; }

// Process <=32 rows whose bounds sit in register BND (lanes 0..31 = row
// starts, lanes 32..63 = row ends): triples via shfl, flat 3-interval
// stream, 2-deep pipelined. (r23/r28/r29 PROVEN machinery.)
#define SCAN_ROWS32(BND, ROWS, QX, QY, QZ, SQ, KEY)                        \
    for (int r0 = 0; r0 < (ROWS); r0 += 3) {                               \
        int i1 = r0 + 1 < (ROWS) ? r0 + 1 : (ROWS) - 1;                    \
        int i2 = r0 + 2 < (ROWS) ? r0 + 2 : (ROWS) - 1;                    \
        int L0 = __shfl(BND, r0, 64), H0 = __shfl(BND, 32 + r0, 64);       \
        int L1 = __shfl(BND, i1, 64), H1 = __shfl(BND, 32 + i1, 64);       \
        int L2 = __shfl(BND, i2, 64), H2 = __shfl(BND, 32 + i2, 64);       \
        int d0 = H0 - L0;                                                  \
        int d1 = (r0 + 1 < (ROWS)) ? H1 - L1 : 0;                          \
        int d2 = (r0 + 2 < (ROWS)) ? H2 - L2 : 0;                          \
        int s01 = d0 + d1, tot = s01 + d2;                                 \
        int t = lane;                                                      \
        if (t < tot) {                                                     \
            int p = t < d0 ? L0 + t : t < s01 ? L1 + (t - d0)              \
                                              : L2 + (t - s01);            \
            float4 rc = rs[p];                                             \
            for (t += 64; t < tot; t += 64) {                              \
                int pn = t < d0 ? L0 + t : t < s01 ? L1 + (t - d0)         \
                                                   : L2 + (t - s01);       \
                float4 rn = rs[pn];                                        \
                EVALQ(rc, QX, QY, QZ, SQ, KEY)                             \
                rc = rn;                                                   \
            }                                                              \
            EVALQ(rc, QX, QY, QZ, SQ, KEY)                                 \
        }                                                                  \
    }

// General rect scan: ONE lane-coop bounds load per <=32 rows, then
// SCAN_ROWS32. (r23/r28/r29 phase-2 machinery, parameterized by query.)
#define SCAN_RECT(xL, xR, yL, yR, QX, QY, QZ, SQ, KEY)                     \
    {   int R = (xR) - (xL) + 1;                                           \
        for (int g = 0; g < R; g += 32) {                                  \
            int rows = R - g; if (rows > 32) rows = 32;                    \
            int xr  = (xL) + g + (l31 < rows ? l31 : rows - 1);            \
            int col = (lane < 32) ? (yL) : ((yR) + 1);                     \
            int b2 = cs[xr * NG + col];                                    \
            SCAN_ROWS32(b2, rows, QX, QY, QZ, SQ, KEY)                     \
        }                                                                  \
    }

// ---- build A1 (r16/r18, PROVEN): wide parallel histogram, global atomics ----
__global__ __launch_bounds__(256) void k_hist(
    const float* __restrict__ preds, const float* __restrict__ gts,
    int* __restrict__ cursor)
{
    int t = blockIdx.x * 256 + threadIdx.x;
    if (t >= 2 * N_PTS) return;
    int cl = t / N_PTS, i = t - cl * N_PTS;
    const float* src = cl ? gts : preds;
    int cell = cellC(src[i*3+0]) * NG + cellC(src[i*3+1]);
    atomicAdd(&cursor[cl * NC + cell], 1);
}

// ---- build A2 (r22, PROVEN): scan via shfl wave-scans, 2 barriers ----
__global__ __launch_bounds__(1024) void k_scan(
    int* __restrict__ cursor, int* __restrict__ bstart)
{
    __shared__ int wsum[16];
    __shared__ int wpre[16];
    int cl = blockIdx.x, t = threadIdx.x;
    int wave = t >> 6, lane = t & 63;

    int base = cl * NC + t * 16;                    // 64B-aligned (ws layout)
    const int4* c4 = (const int4*)(cursor + base);
    int4 a = c4[0], b = c4[1], c = c4[2], d = c4[3];
    int v[16] = { a.x, a.y, a.z, a.w, b.x, b.y, b.z, b.w,
                  c.x, c.y, c.z, c.w, d.x, d.y, d.z, d.w };
    int s = 0;
    #pragma unroll
    for (int i = 0; i < 16; ++i) s += v[i];

    int ps = s;                                     // inclusive 64-lane scan
    #pragma unroll
    for (int m = 1; m < 64; m <<= 1) {
        int o = __shfl_up(ps, m, 64);
        if (lane >= m) ps += o;
    }
    if (lane == 63) wsum[wave] = ps;
    __syncthreads();
    if (t < 16) {
        int x = wsum[t];
        int px = x;                                 // inclusive 16-scan
        #pragma unroll
        for (int m = 1; m < 16; m <<= 1) {
            int o = __shfl_up(px, m, 16);
            if ((t & 15) >= m) px += o;
        }
        wpre[t] = px - x;                           // exclusive wave prefix
    }
    __syncthreads();

    int run = wpre[wave] + (ps - s);                // exclusive thread prefix
    #pragma unroll
    for (int i = 0; i < 16; ++i) {
        bstart[cl * (NC + 1) + t * 16 + i] = run;
        cursor[base + i] = run;
        run += v[i];
    }
    if (t == 1023) bstart[cl * (NC + 1) + NC] = run;   // == N_PTS
}

// ---- build B (r15/r18, PROVEN): wide scatter into cell-sorted order ----
__global__ __launch_bounds__(256) void k_scatter(
    const float* __restrict__ preds, const float* __restrict__ gts,
    int* __restrict__ cursor, float4* __restrict__ sorted)
{
    int t = blockIdx.x * 256 + threadIdx.x;
    if (t >= 2 * N_PTS) return;
    int cl = t / N_PTS, i = t - cl * N_PTS;
    const float* src = cl ? gts : preds;
    float x = src[i*3+0], y = src[i*3+1], z = src[i*3+2];
    int cell = cellC(x) * NG + cellC(y);
    int pos = atomicAdd(&cursor[cl * NC + cell], 1);
    sorted[(size_t)cl * N_PTS + pos] = make_float4(x, y, z, __int_as_float(i));
}

// ---- main (FINAL == r29 EXACT, best verified: 118.68/119.13us total,
// k_main ~50us). Session conclusion: k_main is pinned ~50us across wave
// count x0.125-1, work x1-5, q/wave 1-2, LDS staging, span phase-2 —
// a latency x residency x tail equilibrium of this algorithm family
// (r31 proved tail/bound governance bidirectionally; r32/r34 closed the
// remaining levers). ~68us of total is fixed harness overhead, proven
// dispatch-count-invariant (r25). Two sequential queries per wave share
// fixed overhead (launch, samp, store) with cross-query ILP on the two
// independent seed-bounds loads; 20000 1-wave blocks keep dynamic HW
// balancing. Numerics bit-identical throughout: numpy-exact P;
// key=(ordmap(P)<<32|idx); wave-min == numpy first-occurrence argmin;
// samp EVALQ gives valid upper bounds (no empty-seed path);
// W-certificate W^2 = d_seed + MARGIN; superset/rescan idempotent.
__global__ __launch_bounds__(64) void k_main(
    const float4* __restrict__ sorted, const int* __restrict__ bstart,
    float* __restrict__ out)
{
    int wid  = blockIdx.x;                                 // 0..19999 (pair)
    int lane = threadIdx.x;                                // 0..63
    int q0   = wid * 2;                                    // N_PTS even =>
    int dir  = q0 / N_PTS;                                 // pair same dir
    int qp0  = q0 - dir * N_PTS;
    int rcl  = 1 - dir;

    const float4* rs = sorted + (size_t)rcl * N_PTS;
    const int*    cs = bstart + rcl * (NC + 1);

    float4 samp = rs[lane * SSTRIDE];                  // independent, early
    float4 qva  = sorted[(size_t)dir * N_PTS + qp0];   // wave-broadcast
    float4 qvb  = sorted[(size_t)dir * N_PTS + qp0 + 1];
    int oa = __float_as_int(qva.w), ob = __float_as_int(qvb.w);
    float qax = qva.x, qay = qva.y, qaz = qva.z;
    float qbx = qvb.x, qby = qvb.y, qbz = qvb.z;
    float sqa = np_self_dot(qax, qay, qaz);
    float sqb = np_self_dot(qbx, qby, qbz);

    unsigned long long ka = ~0ULL, kb = ~0ULL;
    int l31 = lane & 31;

    // both 5x5 seed boxes; BOTH bounds loads issued before either stream
    int cxa = cellC(qax), cya = cellC(qay);
    int cxb = cellC(qbx), cyb = cellC(qby);
    int sxLa = cxa > 1 ? cxa - 2 : 0, sxRa = cxa < NG-2 ? cxa + 2 : NG-1;
    int syLa = cya > 1 ? cya - 2 : 0, syRa = cya < NG-2 ? cya + 2 : NG-1;
    int sxLb = cxb > 1 ? cxb - 2 : 0, sxRb = cxb < NG-2 ? cxb + 2 : NG-1;
    int syLb = cyb > 1 ? cyb - 2 : 0, syRb = cyb < NG-2 ? cyb + 2 : NG-1;
    int nrsA = sxRa - sxLa + 1, nrsB = sxRb - sxLb + 1;    // 3..5
    int xrA  = sxLa + (l31 < nrsA ? l31 : nrsA - 1);
    int xrB  = sxLb + (l31 < nrsB ? l31 : nrsB - 1);
    int colA = (lane < 32) ? syLa : (syRa + 1);
    int colB = (lane < 32) ? syLb : (syRb + 1);
    int bndA = cs[xrA * NG + colA];                        // 2 loads
    int bndB = cs[xrB * NG + colB];                        //  in flight

    SCAN_ROWS32(bndA, nrsA, qax, qay, qaz, sqa, ka)        // seed A
    SCAN_ROWS32(bndB, nrsB, qbx, qby, qbz, sqb, kb)        // seed B
    EVALQ(samp, qax, qay, qaz, sqa, ka)     // valid upper bound for A
    EVALQ(samp, qbx, qby, qbz, sqb, kb)     // valid upper bound for B

    ka = wave_min_u64(ka);
    kb = wave_min_u64(kb);

    // phase 2 per query — rare with the 5x5 seed (W ~ 1.3 cells typical)
    float Wa = sqrtf(invord((unsigned)(ka >> 32)) + MARGIN);
    float Wb = sqrtf(invord((unsigned)(kb >> 32)) + MARGIN);
    int txLa = cellC(qax - Wa), txRa = cellC(qax + Wa);
    int tyLa = cellC(qay - Wa), tyRa = cellC(qay + Wa);
    int txLb = cellC(qbx - Wb), txRb = cellC(qbx + Wb);
    int tyLb = cellC(qby - Wb), tyRb = cellC(qby + Wb);
    if (!(txLa >= sxLa && txRa <= sxRa && tyLa >= syLa && tyRa <= syRa)) {
        SCAN_RECT(txLa, txRa, tyLa, tyRa, qax, qay, qaz, sqa, ka)
        ka = wave_min_u64(ka);
    }
    if (!(txLb >= sxLb && txRb <= sxRb && tyLb >= syLb && tyRb <= syRb)) {
        SCAN_RECT(txLb, txRb, tyLb, tyRb, qbx, qby, qbz, sqb, kb)
        kb = wave_min_u64(kb);
    }

    if (lane == 0) {
        out[dir * N_PTS + oa]       = invord((unsigned)(ka >> 32));
        out[(2 + dir) * N_PTS + oa] = (float)(unsigned)(ka & 0xFFFFFFFFu);
        out[dir * N_PTS + ob]       = invord((unsigned)(kb >> 32));
        out[(2 + dir) * N_PTS + ob] = (float)(unsigned)(kb & 0xFFFFFFFFu);
    }
}

// ---- fallback (tiny workspace): brute-force direct kernel (proven r2) ----
__device__ __forceinline__ float np_pair(float sq, float sr,
                                         float qx, float qy, float qz,
                                         float rx, float ry, float rz) {
    float zz = __fadd_rn(__fadd_rn(__fmul_rn(qx, rx), __fmul_rn(qy, ry)),
                         __fmul_rn(qz, rz));
    return __fsub_rn(__fadd_rn(sq, sr), __fadd_rn(zz, zz));
}

__global__ __launch_bounds__(256) void chamfer_direct_kernel(
    const float* __restrict__ preds, const float* __restrict__ gts,
    float* __restrict__ out)
{
    __shared__ float4 spts[256];
    int bid = blockIdx.x;
    int dir = bid / QB79;
    int qb  = bid - dir * QB79;
    int q   = qb * 256 + threadIdx.x;

    const float* qpts = (dir == 0) ? preds : gts;
    const float* rpts = (dir == 0) ? gts   : preds;

    int qc = (q < N_PTS) ? q : (N_PTS - 1);
    float qx = qpts[qc*3+0], qy = qpts[qc*3+1], qz = qpts[qc*3+2];
    float sq = np_self_dot(qx, qy, qz);
    float best = 3.4e38f;
    int   bidx = 0;

    for (int t = 0; t < N_PTS; t += 256) {
        int cnt = min(256, N_PTS - t);
        __syncthreads();
        if ((int)threadIdx.x < cnt) {
            int j = t + threadIdx.x;
            float rx = rpts[j*3+0], ry = rpts[j*3+1], rz = rpts[j*3+2];
            spts[threadIdx.x] = make_float4(rx, ry, rz, np_self_dot(rx, ry, rz));
        }
        __syncthreads();
        for (int k = 0; k < cnt; ++k) {
            float4 r = spts[k];
            float d = np_pair(sq, r.w, qx, qy, qz, r.x, r.y, r.z);
            if (d < best) { best = d; bidx = t + k; }
        }
    }
    if (q < N_PTS) {
        out[dir * N_PTS + q]       = best;
        out[(2 + dir) * N_PTS + q] = (float)bidx;
    }
}

extern "C" void kernel_launch(void* const* d_in, const int* in_sizes, int n_in,
                              void* d_out, int out_size, void* d_ws, size_t ws_size,
                              hipStream_t stream) {
    const float* preds = (const float*)d_in[0];  // [20000, 3]
    const float* gts   = (const float*)d_in[1];  // [1, 20000, 3]
    float* out = (float*)d_out;

    char* w = (char*)d_ws;
    size_t sorted_b = (size_t)2 * N_PTS * sizeof(float4);   // 640000
    size_t bstart_b = (size_t)2 * (NC + 1) * sizeof(int);   // 131080
    size_t cursor_b = (size_t)2 * NC * sizeof(int);         // 131072
    size_t need = sorted_b + bstart_b + cursor_b;

    if (ws_size >= need) {
        float4* sorted = (float4*)w;
        int* bstart = (int*)(w + sorted_b);
        int* cursor = (int*)(w + sorted_b + bstart_b);

        hipMemsetAsync(cursor, 0, cursor_b, stream);
        k_hist<<<(2 * N_PTS + 255) / 256, 256, 0, stream>>>(preds, gts, cursor);
        k_scan<<<2, 1024, 0, stream>>>(cursor, bstart);
        k_scatter<<<(2 * N_PTS + 255) / 256, 256, 0, stream>>>(
            preds, gts, cursor, sorted);
        k_main<<<N_PTS, 64, 0, stream>>>(sorted, bstart, out);
    } else {
        chamfer_direct_kernel<<<2 * QB79, 256, 0, stream>>>(preds, gts, out);
    }
}